// Round 2
// baseline (4637.862 us; speedup 1.0000x reference)
//
#include <hip/hip_runtime.h>

#define NN 50000
#define NE 800000
#define ETOT (NE + NN)

__device__ __forceinline__ float bcast(float v, int lane) {
  return __int_as_float(__builtin_amdgcn_readlane(__float_as_int(v), lane));
}

// ---------------- CSR build ----------------

__global__ void k_deg_init(int* __restrict__ deg) {
  int i = blockIdx.x * 256 + threadIdx.x;
  if (i < NN) deg[i] = 1;  // self loop
}

__global__ void k_deg(const int* __restrict__ dst, int* __restrict__ deg) {
  int e = blockIdx.x * 256 + threadIdx.x;
  if (e < NE) atomicAdd(&deg[dst[e]], 1);
}

// single-block exclusive scan over deg -> offsets[NN+1]
__global__ void k_scan(const int* __restrict__ deg, int* __restrict__ offsets) {
  __shared__ int wsum[16];
  __shared__ int carry;
  const int t = threadIdx.x, lane = t & 63, w = t >> 6;
  if (t == 0) carry = 0;
  __syncthreads();
  for (int base = 0; base < NN; base += 1024) {
    const int i = base + t;
    int v = (i < NN) ? deg[i] : 0;
    int x = v;
#pragma unroll
    for (int d = 1; d < 64; d <<= 1) {
      int y = __shfl_up(x, d, 64);
      if (lane >= d) x += y;
    }
    if (lane == 63) wsum[w] = x;
    __syncthreads();
    if (t < 16) {
      int z = wsum[t];
#pragma unroll
      for (int d = 1; d < 16; d <<= 1) {
        int y = __shfl_up(z, d, 64);
        if (t >= d) z += y;
      }
      wsum[t] = z;
    }
    __syncthreads();
    const int cb = carry;
    const int prev = (w > 0) ? wsum[w - 1] : 0;
    if (i < NN) offsets[i] = cb + prev + x - v;  // exclusive
    const int ctot = wsum[15];
    __syncthreads();
    if (t == 0) carry = cb + ctot;
    __syncthreads();
  }
  if (t == 0) offsets[NN] = carry;  // == ETOT
}

__global__ void k_self(const int* __restrict__ offsets, int* __restrict__ ssrc,
                       int* __restrict__ cursor) {
  int i = blockIdx.x * 256 + threadIdx.x;
  if (i < NN) {
    int o = offsets[i];
    ssrc[o] = i;          // self loop first in segment
    cursor[i] = o + 1;
  }
}

__global__ void k_scatter(const int* __restrict__ src, const int* __restrict__ dst,
                          int* __restrict__ cursor, int* __restrict__ ssrc) {
  int e = blockIdx.x * 256 + threadIdx.x;
  if (e < NE) {
    int p = atomicAdd(&cursor[dst[e]], 1);
    ssrc[p] = src[e];
  }
}

// ---------------- node projections: h = relu(xW_in+b); a_src/a_dst/v ----------------

__global__ __launch_bounds__(256) void k_node_proj(
    const float* __restrict__ x, const float* __restrict__ W_in, const float* __restrict__ b_in,
    const float* __restrict__ W_lin, const float* __restrict__ W_src, const float* __restrict__ W_dst,
    float* __restrict__ a_src, float* __restrict__ a_dst, float* __restrict__ v) {
  const int c = threadIdx.x & 63;
  const int n = blockIdx.x * 4 + (threadIdx.x >> 6);
  if (n >= NN) return;
  const float xc = x[n * 64 + c];
  float w[64];
  // h = relu(x @ W_in + b_in)
#pragma unroll
  for (int k = 0; k < 64; ++k) w[k] = W_in[k * 64 + c];
  float h0 = b_in[c], h1 = 0.f, h2 = 0.f, h3 = 0.f;
#pragma unroll
  for (int k = 0; k < 64; k += 4) {
    h0 = fmaf(bcast(xc, k + 0), w[k + 0], h0);
    h1 = fmaf(bcast(xc, k + 1), w[k + 1], h1);
    h2 = fmaf(bcast(xc, k + 2), w[k + 2], h2);
    h3 = fmaf(bcast(xc, k + 3), w[k + 3], h3);
  }
  const float h = fmaxf((h0 + h1) + (h2 + h3), 0.f);
  // a_src = h @ W_src
#pragma unroll
  for (int k = 0; k < 64; ++k) w[k] = W_src[k * 64 + c];
  float a0 = 0.f, a1 = 0.f, a2 = 0.f, a3 = 0.f;
#pragma unroll
  for (int k = 0; k < 64; k += 4) {
    a0 = fmaf(bcast(h, k + 0), w[k + 0], a0);
    a1 = fmaf(bcast(h, k + 1), w[k + 1], a1);
    a2 = fmaf(bcast(h, k + 2), w[k + 2], a2);
    a3 = fmaf(bcast(h, k + 3), w[k + 3], a3);
  }
  a_src[n * 64 + c] = (a0 + a1) + (a2 + a3);
  // a_dst = h @ W_dst
#pragma unroll
  for (int k = 0; k < 64; ++k) w[k] = W_dst[k * 64 + c];
  a0 = a1 = a2 = a3 = 0.f;
#pragma unroll
  for (int k = 0; k < 64; k += 4) {
    a0 = fmaf(bcast(h, k + 0), w[k + 0], a0);
    a1 = fmaf(bcast(h, k + 1), w[k + 1], a1);
    a2 = fmaf(bcast(h, k + 2), w[k + 2], a2);
    a3 = fmaf(bcast(h, k + 3), w[k + 3], a3);
  }
  a_dst[n * 64 + c] = (a0 + a1) + (a2 + a3);
  // v = h @ W_lin
#pragma unroll
  for (int k = 0; k < 64; ++k) w[k] = W_lin[k * 64 + c];
  a0 = a1 = a2 = a3 = 0.f;
#pragma unroll
  for (int k = 0; k < 64; k += 4) {
    a0 = fmaf(bcast(h, k + 0), w[k + 0], a0);
    a1 = fmaf(bcast(h, k + 1), w[k + 1], a1);
    a2 = fmaf(bcast(h, k + 2), w[k + 2], a2);
    a3 = fmaf(bcast(h, k + 3), w[k + 3], a3);
  }
  v[n * 64 + c] = (a0 + a1) + (a2 + a3);
}

// ---------------- conv: per-node online softmax aggregation ----------------
// wave = one destination node; lane = one channel. Weight columns live in VGPRs.

__global__ void k_conv(
    const float* __restrict__ pos,
    const float* __restrict__ Wp1, const float* __restrict__ bp1,
    const float* __restrict__ Wp2, const float* __restrict__ bp2,
    const float* __restrict__ Wa1, const float* __restrict__ ba1,
    const float* __restrict__ Wa2, const float* __restrict__ ba2,
    const float* __restrict__ a_src, const float* __restrict__ a_dst,
    const float* __restrict__ v,
    const int* __restrict__ offsets, const int* __restrict__ ssrc,
    float* __restrict__ o_pt) {
  const int c = threadIdx.x & 63;
  const int n = blockIdx.x * 4 + (threadIdx.x >> 6);
  if (n >= NN) return;

  float wp1[6], wp2[64], wa1[64], wa2[64];
#pragma unroll
  for (int d = 0; d < 6; ++d) wp1[d] = Wp1[d * 64 + c];
#pragma unroll
  for (int k = 0; k < 64; ++k) wp2[k] = Wp2[k * 64 + c];
#pragma unroll
  for (int k = 0; k < 64; ++k) wa1[k] = Wa1[k * 64 + c];
#pragma unroll
  for (int k = 0; k < 64; ++k) wa2[k] = Wa2[k * 64 + c];
  const float bp1c = bp1[c], bp2c = bp2[c];
  const float ba1c = ba1[c], ba2c = ba2[c];

  float pi[6];
  {
    const float2* p2 = (const float2*)(pos + n * 6);
    float2 a = p2[0], b = p2[1], cc = p2[2];
    pi[0] = a.x; pi[1] = a.y; pi[2] = b.x; pi[3] = b.y; pi[4] = cc.x; pi[5] = cc.y;
  }
  const float adc = a_dst[n * 64 + c];
  const int e0 = __builtin_amdgcn_readfirstlane(offsets[n]);
  const int e1 = __builtin_amdgcn_readfirstlane(offsets[n + 1]);

  float m = 0.f, s = 0.f, acc = 0.f;  // alpha >= 0 (relu), so m=0 init is exact
  for (int e = e0; e < e1; ++e) {
    const int j = __builtin_amdgcn_readfirstlane(ssrc[e]);
    const float asc = a_src[j * 64 + c];
    const float vjc = v[j * 64 + c];
    float pd[6];
    {
      const float2* p2 = (const float2*)(pos + j * 6);
      float2 a = p2[0], b = p2[1], cc = p2[2];
      pd[0] = pi[0] - a.x; pd[1] = pi[1] - a.y;
      pd[2] = pi[2] - b.x; pd[3] = pi[3] - b.y;
      pd[4] = pi[4] - cc.x; pd[5] = pi[5] - cc.y;
    }
    // hidden_p[lane] = relu(bp1 + pd . Wp1[:,lane])
    float hp = bp1c;
#pragma unroll
    for (int d = 0; d < 6; ++d) hp = fmaf(pd[d], wp1[d], hp);
    hp = fmaxf(hp, 0.f);
    // delta[lane] = relu(bp2 + sum_k hp[k] * Wp2[k,lane])
    float d0 = 0.f, d1 = 0.f, d2 = 0.f, d3 = 0.f;
#pragma unroll
    for (int k = 0; k < 64; k += 4) {
      d0 = fmaf(bcast(hp, k + 0), wp2[k + 0], d0);
      d1 = fmaf(bcast(hp, k + 1), wp2[k + 1], d1);
      d2 = fmaf(bcast(hp, k + 2), wp2[k + 2], d2);
      d3 = fmaf(bcast(hp, k + 3), wp2[k + 3], d3);
    }
    const float delta = fmaxf(bp2c + ((d0 + d1) + (d2 + d3)), 0.f);
    // u[lane] = a_dst_i - a_src_j + delta
    const float u = (adc - asc) + delta;
    // hidden_a[lane] = relu(ba1 + sum_k u[k] * Wa1[k,lane])
    d0 = d1 = d2 = d3 = 0.f;
#pragma unroll
    for (int k = 0; k < 64; k += 4) {
      d0 = fmaf(bcast(u, k + 0), wa1[k + 0], d0);
      d1 = fmaf(bcast(u, k + 1), wa1[k + 1], d1);
      d2 = fmaf(bcast(u, k + 2), wa1[k + 2], d2);
      d3 = fmaf(bcast(u, k + 3), wa1[k + 3], d3);
    }
    const float ha = fmaxf(ba1c + ((d0 + d1) + (d2 + d3)), 0.f);
    // alpha[lane] = relu(ba2 + sum_k ha[k] * Wa2[k,lane])
    d0 = d1 = d2 = d3 = 0.f;
#pragma unroll
    for (int k = 0; k < 64; k += 4) {
      d0 = fmaf(bcast(ha, k + 0), wa2[k + 0], d0);
      d1 = fmaf(bcast(ha, k + 1), wa2[k + 1], d1);
      d2 = fmaf(bcast(ha, k + 2), wa2[k + 2], d2);
      d3 = fmaf(bcast(ha, k + 3), wa2[k + 3], d3);
    }
    const float alpha = fmaxf(ba2c + ((d0 + d1) + (d2 + d3)), 0.f);
    // online softmax (per channel)
    const float mn = fmaxf(m, alpha);
    const float sc = __expf(m - mn);
    const float wv = __expf(alpha - mn);
    s = fmaf(s, sc, wv);
    acc = fmaf(acc, sc, wv * (vjc + delta));
    m = mn;
  }
  o_pt[n * 64 + c] = acc / (s + 1e-16f);
}

// ---------------- epilogue: out = relu(o_pt @ W_out + b_out) + x ----------------

__global__ __launch_bounds__(256) void k_out(
    const float* __restrict__ o_pt, const float* __restrict__ W_out,
    const float* __restrict__ b_out, const float* __restrict__ x,
    float* __restrict__ out) {
  const int c = threadIdx.x & 63;
  const int n = blockIdx.x * 4 + (threadIdx.x >> 6);
  if (n >= NN) return;
  const float oc = o_pt[n * 64 + c];
  float w[64];
#pragma unroll
  for (int k = 0; k < 64; ++k) w[k] = W_out[k * 64 + c];
  float a0 = b_out[c], a1 = 0.f, a2 = 0.f, a3 = 0.f;
#pragma unroll
  for (int k = 0; k < 64; k += 4) {
    a0 = fmaf(bcast(oc, k + 0), w[k + 0], a0);
    a1 = fmaf(bcast(oc, k + 1), w[k + 1], a1);
    a2 = fmaf(bcast(oc, k + 2), w[k + 2], a2);
    a3 = fmaf(bcast(oc, k + 3), w[k + 3], a3);
  }
  out[n * 64 + c] = fmaxf((a0 + a1) + (a2 + a3), 0.f) + x[n * 64 + c];
}

// ---------------- launch ----------------

extern "C" void kernel_launch(void* const* d_in, const int* in_sizes, int n_in,
                              void* d_out, int out_size, void* d_ws, size_t ws_size,
                              hipStream_t stream) {
  const float* x     = (const float*)d_in[0];
  const float* pos   = (const float*)d_in[1];
  const int*   ei    = (const int*)d_in[2];
  const float* W_in  = (const float*)d_in[3];
  const float* b_in  = (const float*)d_in[4];
  const float* W_out = (const float*)d_in[5];
  const float* b_out = (const float*)d_in[6];
  const float* W_lin = (const float*)d_in[7];
  const float* W_src = (const float*)d_in[8];
  const float* W_dst = (const float*)d_in[9];
  const float* Wp1   = (const float*)d_in[10];
  const float* bp1   = (const float*)d_in[11];
  const float* Wp2   = (const float*)d_in[12];
  const float* bp2   = (const float*)d_in[13];
  const float* Wa1   = (const float*)d_in[14];
  const float* ba1   = (const float*)d_in[15];
  const float* Wa2   = (const float*)d_in[16];
  const float* ba2   = (const float*)d_in[17];

  float* a_src = (float*)d_ws;             // NN*64
  float* a_dst = a_src + NN * 64;          // NN*64
  float* vv    = a_dst + NN * 64;          // NN*64
  float* o_pt  = vv + NN * 64;             // NN*64
  int* deg     = (int*)(o_pt + NN * 64);   // NN
  int* offsets = deg + NN;                 // NN+1
  int* cursor  = offsets + NN + 1;         // NN
  int* ssrc    = cursor + NN;              // ETOT

  const int* esrc = ei;
  const int* edst = ei + NE;

  k_deg_init<<<(NN + 255) / 256, 256, 0, stream>>>(deg);
  k_node_proj<<<NN / 4, 256, 0, stream>>>(x, W_in, b_in, W_lin, W_src, W_dst,
                                          a_src, a_dst, vv);
  k_deg<<<(NE + 255) / 256, 256, 0, stream>>>(edst, deg);
  k_scan<<<1, 1024, 0, stream>>>(deg, offsets);
  k_self<<<(NN + 255) / 256, 256, 0, stream>>>(offsets, ssrc, cursor);
  k_scatter<<<(NE + 255) / 256, 256, 0, stream>>>(esrc, edst, cursor, ssrc);
  k_conv<<<NN / 4, 256, 0, stream>>>(pos, Wp1, bp1, Wp2, bp2, Wa1, ba1, Wa2, ba2,
                                     a_src, a_dst, vv, offsets, ssrc, o_pt);
  k_out<<<NN / 4, 256, 0, stream>>>(o_pt, W_out, b_out, x, (float*)d_out);
}

// Round 3
// 987.169 us; speedup vs baseline: 4.6981x; 4.6981x over previous
//
#include <hip/hip_runtime.h>

#define NN 50000
#define NE 800000
#define ETOT (NE + NN)

__device__ __forceinline__ float bcast(float v, int lane) {
  return __int_as_float(__builtin_amdgcn_readlane(__float_as_int(v), lane));
}

// ---------------- CSR build ----------------

__global__ void k_deg_init(int* __restrict__ deg) {
  int i = blockIdx.x * 256 + threadIdx.x;
  if (i < NN) deg[i] = 1;  // self loop
}

__global__ void k_deg(const int* __restrict__ dst, int* __restrict__ deg) {
  int e = blockIdx.x * 256 + threadIdx.x;
  if (e < NE) atomicAdd(&deg[dst[e]], 1);
}

// single-block exclusive scan over deg -> offsets[NN+1]
__global__ void k_scan(const int* __restrict__ deg, int* __restrict__ offsets) {
  __shared__ int wsum[16];
  __shared__ int carry;
  const int t = threadIdx.x, lane = t & 63, w = t >> 6;
  if (t == 0) carry = 0;
  __syncthreads();
  for (int base = 0; base < NN; base += 1024) {
    const int i = base + t;
    int v = (i < NN) ? deg[i] : 0;
    int x = v;
#pragma unroll
    for (int d = 1; d < 64; d <<= 1) {
      int y = __shfl_up(x, d, 64);
      if (lane >= d) x += y;
    }
    if (lane == 63) wsum[w] = x;
    __syncthreads();
    if (t < 16) {
      int z = wsum[t];
#pragma unroll
      for (int d = 1; d < 16; d <<= 1) {
        int y = __shfl_up(z, d, 64);
        if (t >= d) z += y;
      }
      wsum[t] = z;
    }
    __syncthreads();
    const int cb = carry;
    const int prev = (w > 0) ? wsum[w - 1] : 0;
    if (i < NN) offsets[i] = cb + prev + x - v;  // exclusive
    const int ctot = wsum[15];
    __syncthreads();
    if (t == 0) carry = cb + ctot;
    __syncthreads();
  }
  if (t == 0) offsets[NN] = carry;  // == ETOT
}

__global__ void k_self(const int* __restrict__ offsets, int* __restrict__ ssrc,
                       int* __restrict__ cursor) {
  int i = blockIdx.x * 256 + threadIdx.x;
  if (i < NN) {
    int o = offsets[i];
    ssrc[o] = i;          // self loop first in segment
    cursor[i] = o + 1;
  }
}

__global__ void k_scatter(const int* __restrict__ src, const int* __restrict__ dst,
                          int* __restrict__ cursor, int* __restrict__ ssrc) {
  int e = blockIdx.x * 256 + threadIdx.x;
  if (e < NE) {
    int p = atomicAdd(&cursor[dst[e]], 1);
    ssrc[p] = src[e];
  }
}

// ---------------- node projections: h = relu(xW_in+b); a_src/a_dst/v ----------------

__global__ __launch_bounds__(256) void k_node_proj(
    const float* __restrict__ x, const float* __restrict__ W_in, const float* __restrict__ b_in,
    const float* __restrict__ W_lin, const float* __restrict__ W_src, const float* __restrict__ W_dst,
    float* __restrict__ a_src, float* __restrict__ a_dst, float* __restrict__ v) {
  const int c = threadIdx.x & 63;
  const int n = blockIdx.x * 4 + (threadIdx.x >> 6);
  if (n >= NN) return;
  const float xc = x[n * 64 + c];
  float w[64];
  // h = relu(x @ W_in + b_in)
#pragma unroll
  for (int k = 0; k < 64; ++k) w[k] = W_in[k * 64 + c];
  float h0 = b_in[c], h1 = 0.f, h2 = 0.f, h3 = 0.f;
#pragma unroll
  for (int k = 0; k < 64; k += 4) {
    h0 = fmaf(bcast(xc, k + 0), w[k + 0], h0);
    h1 = fmaf(bcast(xc, k + 1), w[k + 1], h1);
    h2 = fmaf(bcast(xc, k + 2), w[k + 2], h2);
    h3 = fmaf(bcast(xc, k + 3), w[k + 3], h3);
  }
  const float h = fmaxf((h0 + h1) + (h2 + h3), 0.f);
  // a_src = h @ W_src
#pragma unroll
  for (int k = 0; k < 64; ++k) w[k] = W_src[k * 64 + c];
  float a0 = 0.f, a1 = 0.f, a2 = 0.f, a3 = 0.f;
#pragma unroll
  for (int k = 0; k < 64; k += 4) {
    a0 = fmaf(bcast(h, k + 0), w[k + 0], a0);
    a1 = fmaf(bcast(h, k + 1), w[k + 1], a1);
    a2 = fmaf(bcast(h, k + 2), w[k + 2], a2);
    a3 = fmaf(bcast(h, k + 3), w[k + 3], a3);
  }
  a_src[n * 64 + c] = (a0 + a1) + (a2 + a3);
  // a_dst = h @ W_dst
#pragma unroll
  for (int k = 0; k < 64; ++k) w[k] = W_dst[k * 64 + c];
  a0 = a1 = a2 = a3 = 0.f;
#pragma unroll
  for (int k = 0; k < 64; k += 4) {
    a0 = fmaf(bcast(h, k + 0), w[k + 0], a0);
    a1 = fmaf(bcast(h, k + 1), w[k + 1], a1);
    a2 = fmaf(bcast(h, k + 2), w[k + 2], a2);
    a3 = fmaf(bcast(h, k + 3), w[k + 3], a3);
  }
  a_dst[n * 64 + c] = (a0 + a1) + (a2 + a3);
  // v = h @ W_lin
#pragma unroll
  for (int k = 0; k < 64; ++k) w[k] = W_lin[k * 64 + c];
  a0 = a1 = a2 = a3 = 0.f;
#pragma unroll
  for (int k = 0; k < 64; k += 4) {
    a0 = fmaf(bcast(h, k + 0), w[k + 0], a0);
    a1 = fmaf(bcast(h, k + 1), w[k + 1], a1);
    a2 = fmaf(bcast(h, k + 2), w[k + 2], a2);
    a3 = fmaf(bcast(h, k + 3), w[k + 3], a3);
  }
  v[n * 64 + c] = (a0 + a1) + (a2 + a3);
}

// ---------------- conv: per-node online softmax aggregation ----------------
// wave = one destination node; lane = one channel. Weight columns live in VGPRs.
// __launch_bounds__(256,2): cap 256 VGPRs (need ~230) — without this the
// compiler assumes 1024-thread blocks, caps at 64 VGPRs, and spills the
// 192-float weight arrays to scratch (round-2: 11.9 GB HBM spill traffic).

__global__ __launch_bounds__(256, 2) void k_conv(
    const float* __restrict__ pos,
    const float* __restrict__ Wp1, const float* __restrict__ bp1,
    const float* __restrict__ Wp2, const float* __restrict__ bp2,
    const float* __restrict__ Wa1, const float* __restrict__ ba1,
    const float* __restrict__ Wa2, const float* __restrict__ ba2,
    const float* __restrict__ a_src, const float* __restrict__ a_dst,
    const float* __restrict__ v,
    const int* __restrict__ offsets, const int* __restrict__ ssrc,
    float* __restrict__ o_pt) {
  const int c = threadIdx.x & 63;
  const int n = blockIdx.x * 4 + (threadIdx.x >> 6);
  if (n >= NN) return;

  float wp1[6], wp2[64], wa1[64], wa2[64];
#pragma unroll
  for (int d = 0; d < 6; ++d) wp1[d] = Wp1[d * 64 + c];
#pragma unroll
  for (int k = 0; k < 64; ++k) wp2[k] = Wp2[k * 64 + c];
#pragma unroll
  for (int k = 0; k < 64; ++k) wa1[k] = Wa1[k * 64 + c];
#pragma unroll
  for (int k = 0; k < 64; ++k) wa2[k] = Wa2[k * 64 + c];
  const float bp1c = bp1[c], bp2c = bp2[c];
  const float ba1c = ba1[c], ba2c = ba2[c];

  float pi[6];
  {
    const float2* p2 = (const float2*)(pos + n * 6);
    float2 a = p2[0], b = p2[1], cc = p2[2];
    pi[0] = a.x; pi[1] = a.y; pi[2] = b.x; pi[3] = b.y; pi[4] = cc.x; pi[5] = cc.y;
  }
  const float adc = a_dst[n * 64 + c];
  const int e0 = __builtin_amdgcn_readfirstlane(offsets[n]);
  const int e1 = __builtin_amdgcn_readfirstlane(offsets[n + 1]);

  float m = 0.f, s = 0.f, acc = 0.f;  // alpha >= 0 (relu), so m=0 init is exact
  for (int e = e0; e < e1; ++e) {
    const int j = __builtin_amdgcn_readfirstlane(ssrc[e]);
    const float asc = a_src[j * 64 + c];
    const float vjc = v[j * 64 + c];
    float pd[6];
    {
      const float2* p2 = (const float2*)(pos + j * 6);
      float2 a = p2[0], b = p2[1], cc = p2[2];
      pd[0] = pi[0] - a.x; pd[1] = pi[1] - a.y;
      pd[2] = pi[2] - b.x; pd[3] = pi[3] - b.y;
      pd[4] = pi[4] - cc.x; pd[5] = pi[5] - cc.y;
    }
    // hidden_p[lane] = relu(bp1 + pd . Wp1[:,lane])
    float hp = bp1c;
#pragma unroll
    for (int d = 0; d < 6; ++d) hp = fmaf(pd[d], wp1[d], hp);
    hp = fmaxf(hp, 0.f);
    // delta[lane] = relu(bp2 + sum_k hp[k] * Wp2[k,lane])
    float d0 = 0.f, d1 = 0.f, d2 = 0.f, d3 = 0.f;
#pragma unroll
    for (int k = 0; k < 64; k += 4) {
      d0 = fmaf(bcast(hp, k + 0), wp2[k + 0], d0);
      d1 = fmaf(bcast(hp, k + 1), wp2[k + 1], d1);
      d2 = fmaf(bcast(hp, k + 2), wp2[k + 2], d2);
      d3 = fmaf(bcast(hp, k + 3), wp2[k + 3], d3);
    }
    const float delta = fmaxf(bp2c + ((d0 + d1) + (d2 + d3)), 0.f);
    // u[lane] = a_dst_i - a_src_j + delta
    const float u = (adc - asc) + delta;
    // hidden_a[lane] = relu(ba1 + sum_k u[k] * Wa1[k,lane])
    d0 = d1 = d2 = d3 = 0.f;
#pragma unroll
    for (int k = 0; k < 64; k += 4) {
      d0 = fmaf(bcast(u, k + 0), wa1[k + 0], d0);
      d1 = fmaf(bcast(u, k + 1), wa1[k + 1], d1);
      d2 = fmaf(bcast(u, k + 2), wa1[k + 2], d2);
      d3 = fmaf(bcast(u, k + 3), wa1[k + 3], d3);
    }
    const float ha = fmaxf(ba1c + ((d0 + d1) + (d2 + d3)), 0.f);
    // alpha[lane] = relu(ba2 + sum_k ha[k] * Wa2[k,lane])
    d0 = d1 = d2 = d3 = 0.f;
#pragma unroll
    for (int k = 0; k < 64; k += 4) {
      d0 = fmaf(bcast(ha, k + 0), wa2[k + 0], d0);
      d1 = fmaf(bcast(ha, k + 1), wa2[k + 1], d1);
      d2 = fmaf(bcast(ha, k + 2), wa2[k + 2], d2);
      d3 = fmaf(bcast(ha, k + 3), wa2[k + 3], d3);
    }
    const float alpha = fmaxf(ba2c + ((d0 + d1) + (d2 + d3)), 0.f);
    // online softmax (per channel)
    const float mn = fmaxf(m, alpha);
    const float sc = __expf(m - mn);
    const float wv = __expf(alpha - mn);
    s = fmaf(s, sc, wv);
    acc = fmaf(acc, sc, wv * (vjc + delta));
    m = mn;
  }
  o_pt[n * 64 + c] = acc / (s + 1e-16f);
}

// ---------------- epilogue: out = relu(o_pt @ W_out + b_out) + x ----------------

__global__ __launch_bounds__(256) void k_out(
    const float* __restrict__ o_pt, const float* __restrict__ W_out,
    const float* __restrict__ b_out, const float* __restrict__ x,
    float* __restrict__ out) {
  const int c = threadIdx.x & 63;
  const int n = blockIdx.x * 4 + (threadIdx.x >> 6);
  if (n >= NN) return;
  const float oc = o_pt[n * 64 + c];
  float w[64];
#pragma unroll
  for (int k = 0; k < 64; ++k) w[k] = W_out[k * 64 + c];
  float a0 = b_out[c], a1 = 0.f, a2 = 0.f, a3 = 0.f;
#pragma unroll
  for (int k = 0; k < 64; k += 4) {
    a0 = fmaf(bcast(oc, k + 0), w[k + 0], a0);
    a1 = fmaf(bcast(oc, k + 1), w[k + 1], a1);
    a2 = fmaf(bcast(oc, k + 2), w[k + 2], a2);
    a3 = fmaf(bcast(oc, k + 3), w[k + 3], a3);
  }
  out[n * 64 + c] = fmaxf((a0 + a1) + (a2 + a3), 0.f) + x[n * 64 + c];
}

// ---------------- launch ----------------

extern "C" void kernel_launch(void* const* d_in, const int* in_sizes, int n_in,
                              void* d_out, int out_size, void* d_ws, size_t ws_size,
                              hipStream_t stream) {
  const float* x     = (const float*)d_in[0];
  const float* pos   = (const float*)d_in[1];
  const int*   ei    = (const int*)d_in[2];
  const float* W_in  = (const float*)d_in[3];
  const float* b_in  = (const float*)d_in[4];
  const float* W_out = (const float*)d_in[5];
  const float* b_out = (const float*)d_in[6];
  const float* W_lin = (const float*)d_in[7];
  const float* W_src = (const float*)d_in[8];
  const float* W_dst = (const float*)d_in[9];
  const float* Wp1   = (const float*)d_in[10];
  const float* bp1   = (const float*)d_in[11];
  const float* Wp2   = (const float*)d_in[12];
  const float* bp2   = (const float*)d_in[13];
  const float* Wa1   = (const float*)d_in[14];
  const float* ba1   = (const float*)d_in[15];
  const float* Wa2   = (const float*)d_in[16];
  const float* ba2   = (const float*)d_in[17];

  float* a_src = (float*)d_ws;             // NN*64
  float* a_dst = a_src + NN * 64;          // NN*64
  float* vv    = a_dst + NN * 64;          // NN*64
  float* o_pt  = vv + NN * 64;             // NN*64
  int* deg     = (int*)(o_pt + NN * 64);   // NN
  int* offsets = deg + NN;                 // NN+1
  int* cursor  = offsets + NN + 1;         // NN
  int* ssrc    = cursor + NN;              // ETOT

  const int* esrc = ei;
  const int* edst = ei + NE;

  k_deg_init<<<(NN + 255) / 256, 256, 0, stream>>>(deg);
  k_node_proj<<<NN / 4, 256, 0, stream>>>(x, W_in, b_in, W_lin, W_src, W_dst,
                                          a_src, a_dst, vv);
  k_deg<<<(NE + 255) / 256, 256, 0, stream>>>(edst, deg);
  k_scan<<<1, 1024, 0, stream>>>(deg, offsets);
  k_self<<<(NN + 255) / 256, 256, 0, stream>>>(offsets, ssrc, cursor);
  k_scatter<<<(NE + 255) / 256, 256, 0, stream>>>(esrc, edst, cursor, ssrc);
  k_conv<<<NN / 4, 256, 0, stream>>>(pos, Wp1, bp1, Wp2, bp2, Wa1, ba1, Wa2, ba2,
                                     a_src, a_dst, vv, offsets, ssrc, o_pt);
  k_out<<<NN / 4, 256, 0, stream>>>(o_pt, W_out, b_out, x, (float*)d_out);
}

// Round 4
// 462.025 us; speedup vs baseline: 10.0381x; 2.1366x over previous
//
#include <hip/hip_runtime.h>

#define NN 50000
#define NE 800000
#define ETOT (NE + NN)

typedef _Float16 f16;
typedef _Float16 v8h __attribute__((ext_vector_type(8)));
typedef float v4f __attribute__((ext_vector_type(4)));

// B-fragment for mfma_f32_16x16x32: lane holds B[k=kb*32+quad*8+i][n=nb*16+(lane&15)]
__device__ __forceinline__ v8h bfrag64(const float* __restrict__ W, int kb, int nb,
                                       int q, int p) {
  const int n = nb * 16 + p;
  const int k0 = kb * 32 + q * 8;
  v8h b;
#pragma unroll
  for (int i = 0; i < 8; ++i) b[i] = (f16)W[(k0 + i) * 64 + n];
  return b;
}

// ---------------- CSR build ----------------

__global__ void k_deg_init(int* __restrict__ deg) {
  int i = blockIdx.x * 256 + threadIdx.x;
  if (i < NN) deg[i] = 1;  // self loop
}

__global__ void k_deg(const int* __restrict__ dst, int* __restrict__ deg) {
  int e = blockIdx.x * 256 + threadIdx.x;
  if (e < NE) atomicAdd(&deg[dst[e]], 1);
}

__global__ void k_scan(const int* __restrict__ deg, int* __restrict__ offsets) {
  __shared__ int wsum[16];
  __shared__ int carry;
  const int t = threadIdx.x, lane = t & 63, w = t >> 6;
  if (t == 0) carry = 0;
  __syncthreads();
  for (int base = 0; base < NN; base += 1024) {
    const int i = base + t;
    int v = (i < NN) ? deg[i] : 0;
    int x = v;
#pragma unroll
    for (int d = 1; d < 64; d <<= 1) {
      int y = __shfl_up(x, d, 64);
      if (lane >= d) x += y;
    }
    if (lane == 63) wsum[w] = x;
    __syncthreads();
    if (t < 16) {
      int z = wsum[t];
#pragma unroll
      for (int d = 1; d < 16; d <<= 1) {
        int y = __shfl_up(z, d, 64);
        if (t >= d) z += y;
      }
      wsum[t] = z;
    }
    __syncthreads();
    const int cb = carry;
    const int prev = (w > 0) ? wsum[w - 1] : 0;
    if (i < NN) offsets[i] = cb + prev + x - v;
    const int ctot = wsum[15];
    __syncthreads();
    if (t == 0) carry = cb + ctot;
    __syncthreads();
  }
  if (t == 0) offsets[NN] = carry;
}

__global__ void k_self(const int* __restrict__ offsets, int* __restrict__ ssrc,
                       int* __restrict__ cursor) {
  int i = blockIdx.x * 256 + threadIdx.x;
  if (i < NN) {
    int o = offsets[i];
    ssrc[o] = i;
    cursor[i] = o + 1;
  }
}

__global__ void k_scatter(const int* __restrict__ src, const int* __restrict__ dst,
                          int* __restrict__ cursor, int* __restrict__ ssrc) {
  int e = blockIdx.x * 256 + threadIdx.x;
  if (e < NE) {
    int p = atomicAdd(&cursor[dst[e]], 1);
    ssrc[p] = src[e];
  }
}

// ---------------- node projections (MFMA): h, then a_src/a_dst/v, and Q = pos@Wp1 ----
// wave = 16 nodes. A-layout load, C-layout store. Per-wave LDS transpose (no barrier:
// same-wave DS ops are in-order).

__global__ __launch_bounds__(256, 2) void k_node(
    const float* __restrict__ x, const float* __restrict__ pos,
    const float* __restrict__ W_in, const float* __restrict__ b_in,
    const float* __restrict__ W_lin, const float* __restrict__ W_src,
    const float* __restrict__ W_dst, const float* __restrict__ Wp1,
    float* __restrict__ a_dst, float* __restrict__ vv,
    f16* __restrict__ asrch, f16* __restrict__ Qh) {
  __shared__ f16 lds[4][16 * 72];
  const int lane = threadIdx.x & 63, w = threadIdx.x >> 6;
  const int q = lane >> 4, p = lane & 15;
  const int base = (blockIdx.x * 4 + w) * 16;
  if (base >= NN) return;

  // x rows in A layout
  v8h xa[2];
#pragma unroll
  for (int kb = 0; kb < 2; ++kb) {
    const float4 f0 = *(const float4*)(x + (base + p) * 64 + kb * 32 + q * 8);
    const float4 f1 = *(const float4*)(x + (base + p) * 64 + kb * 32 + q * 8 + 4);
    v8h a;
    a[0] = (f16)f0.x; a[1] = (f16)f0.y; a[2] = (f16)f0.z; a[3] = (f16)f0.w;
    a[4] = (f16)f1.x; a[5] = (f16)f1.y; a[6] = (f16)f1.z; a[7] = (f16)f1.w;
    xa[kb] = a;
  }
  // h = relu(x@W_in + b_in) -> LDS (C->A transpose)
#pragma unroll
  for (int nb = 0; nb < 4; ++nb) {
    v4f c = {0.f, 0.f, 0.f, 0.f};
    c = __builtin_amdgcn_mfma_f32_16x16x32_f16(xa[0], bfrag64(W_in, 0, nb, q, p), c, 0, 0, 0);
    c = __builtin_amdgcn_mfma_f32_16x16x32_f16(xa[1], bfrag64(W_in, 1, nb, q, p), c, 0, 0, 0);
    const float bi = b_in[p + 16 * nb];
#pragma unroll
    for (int r = 0; r < 4; ++r)
      lds[w][(q * 4 + r) * 72 + p + 16 * nb] = (f16)fmaxf(c[r] + bi, 0.f);
  }
  v8h hA[2];
#pragma unroll
  for (int kb = 0; kb < 2; ++kb)
    hA[kb] = *(const v8h*)&lds[w][p * 72 + kb * 32 + q * 8];

  // a_src = h @ W_src  (store f16)
#pragma unroll
  for (int nb = 0; nb < 4; ++nb) {
    v4f c = {0.f, 0.f, 0.f, 0.f};
    c = __builtin_amdgcn_mfma_f32_16x16x32_f16(hA[0], bfrag64(W_src, 0, nb, q, p), c, 0, 0, 0);
    c = __builtin_amdgcn_mfma_f32_16x16x32_f16(hA[1], bfrag64(W_src, 1, nb, q, p), c, 0, 0, 0);
#pragma unroll
    for (int r = 0; r < 4; ++r)
      asrch[(base + q * 4 + r) * 64 + p + 16 * nb] = (f16)c[r];
  }
  // a_dst = h @ W_dst  (f32)
#pragma unroll
  for (int nb = 0; nb < 4; ++nb) {
    v4f c = {0.f, 0.f, 0.f, 0.f};
    c = __builtin_amdgcn_mfma_f32_16x16x32_f16(hA[0], bfrag64(W_dst, 0, nb, q, p), c, 0, 0, 0);
    c = __builtin_amdgcn_mfma_f32_16x16x32_f16(hA[1], bfrag64(W_dst, 1, nb, q, p), c, 0, 0, 0);
#pragma unroll
    for (int r = 0; r < 4; ++r)
      a_dst[(base + q * 4 + r) * 64 + p + 16 * nb] = c[r];
  }
  // v = h @ W_lin  (f32)
#pragma unroll
  for (int nb = 0; nb < 4; ++nb) {
    v4f c = {0.f, 0.f, 0.f, 0.f};
    c = __builtin_amdgcn_mfma_f32_16x16x32_f16(hA[0], bfrag64(W_lin, 0, nb, q, p), c, 0, 0, 0);
    c = __builtin_amdgcn_mfma_f32_16x16x32_f16(hA[1], bfrag64(W_lin, 1, nb, q, p), c, 0, 0, 0);
#pragma unroll
    for (int r = 0; r < 4; ++r)
      vv[(base + q * 4 + r) * 64 + p + 16 * nb] = c[r];
  }
  // Q = pos @ Wp1  (K=6 padded to 32, f16 store)
  v8h pa;
#pragma unroll
  for (int i = 0; i < 8; ++i) {
    const int k = q * 8 + i;
    pa[i] = (k < 6) ? (f16)pos[(base + p) * 6 + k] : (f16)0.f;
  }
#pragma unroll
  for (int nb = 0; nb < 4; ++nb) {
    v8h b;
#pragma unroll
    for (int i = 0; i < 8; ++i) {
      const int k = q * 8 + i;
      b[i] = (k < 6) ? (f16)Wp1[k * 64 + nb * 16 + p] : (f16)0.f;
    }
    v4f c = {0.f, 0.f, 0.f, 0.f};
    c = __builtin_amdgcn_mfma_f32_16x16x32_f16(pa, b, c, 0, 0, 0);
#pragma unroll
    for (int r = 0; r < 4; ++r)
      Qh[(base + q * 4 + r) * 64 + p + 16 * nb] = (f16)c[r];
  }
}

// ---------------- conv: wave = dst node, MFMA over 16-edge chunks ----------------

__global__ __launch_bounds__(256, 2) void k_conv(
    const f16* __restrict__ Qh, const float* __restrict__ bp1,
    const float* __restrict__ Wp2, const float* __restrict__ bp2,
    const float* __restrict__ Wa1, const float* __restrict__ ba1,
    const float* __restrict__ Wa2, const float* __restrict__ ba2,
    const f16* __restrict__ asrch, const float* __restrict__ a_dst,
    const float* __restrict__ v,
    const int* __restrict__ offsets, const int* __restrict__ ssrc,
    float* __restrict__ o_pt) {
  __shared__ f16 lds[4][2][16 * 72];
  const int lane = threadIdx.x & 63, w = threadIdx.x >> 6;
  const int q = lane >> 4, p = lane & 15;
  const int n = blockIdx.x * 4 + w;  // grid = NN/4 exactly

  // weight fragments (B layout), resident in VGPRs: 24 frags = 96 VGPRs
  v8h fWp2[4][2], fWa1[4][2], fWa2[4][2];
#pragma unroll
  for (int nb = 0; nb < 4; ++nb)
#pragma unroll
    for (int kb = 0; kb < 2; ++kb) {
      fWp2[nb][kb] = bfrag64(Wp2, kb, nb, q, p);
      fWa1[nb][kb] = bfrag64(Wa1, kb, nb, q, p);
      fWa2[nb][kb] = bfrag64(Wa2, kb, nb, q, p);
    }
  float bp2C[4], ba1C[4], ba2C[4];
#pragma unroll
  for (int nb = 0; nb < 4; ++nb) {
    bp2C[nb] = bp2[p + 16 * nb];
    ba1C[nb] = ba1[p + 16 * nb];
    ba2C[nb] = ba2[p + 16 * nb];
  }
  // node-i quantities in A-layout channels (ch = kb*32 + q*8 + i)
  float QiA[16], adcA[16];
#pragma unroll
  for (int kb = 0; kb < 2; ++kb) {
    const v8h qv = *(const v8h*)(Qh + n * 64 + kb * 32 + q * 8);
    const float4 b0 = *(const float4*)(bp1 + kb * 32 + q * 8);
    const float4 b1 = *(const float4*)(bp1 + kb * 32 + q * 8 + 4);
    QiA[kb * 8 + 0] = (float)qv[0] + b0.x; QiA[kb * 8 + 1] = (float)qv[1] + b0.y;
    QiA[kb * 8 + 2] = (float)qv[2] + b0.z; QiA[kb * 8 + 3] = (float)qv[3] + b0.w;
    QiA[kb * 8 + 4] = (float)qv[4] + b1.x; QiA[kb * 8 + 5] = (float)qv[5] + b1.y;
    QiA[kb * 8 + 6] = (float)qv[6] + b1.z; QiA[kb * 8 + 7] = (float)qv[7] + b1.w;
    const float4 d0 = *(const float4*)(a_dst + n * 64 + kb * 32 + q * 8);
    const float4 d1 = *(const float4*)(a_dst + n * 64 + kb * 32 + q * 8 + 4);
    adcA[kb * 8 + 0] = d0.x; adcA[kb * 8 + 1] = d0.y;
    adcA[kb * 8 + 2] = d0.z; adcA[kb * 8 + 3] = d0.w;
    adcA[kb * 8 + 4] = d1.x; adcA[kb * 8 + 5] = d1.y;
    adcA[kb * 8 + 6] = d1.z; adcA[kb * 8 + 7] = d1.w;
  }
  const int e0 = __builtin_amdgcn_readfirstlane(offsets[n]);
  const int e1 = __builtin_amdgcn_readfirstlane(offsets[n + 1]);
  const int cnt = e1 - e0;

  float m_[4], s_[4], ac_[4];
#pragma unroll
  for (int nb = 0; nb < 4; ++nb) { m_[nb] = 0.f; s_[nb] = 0.f; ac_[nb] = 0.f; }

  for (int cb = 0; cb < cnt; cb += 16) {
    const int jA = ssrc[e0 + min(cb + p, cnt - 1)];  // A-layout edge = p
    int jC[4]; bool okC[4];
#pragma unroll
    for (int r = 0; r < 4; ++r) {  // C-layout edges = q*4+r
      const int t = cb + q * 4 + r;
      okC[r] = t < cnt;
      jC[r] = ssrc[e0 + min(t, cnt - 1)];
    }
    // hp = relu(Qi + bp1 - Qj)  in A layout
    v8h uA[2];
#pragma unroll
    for (int kb = 0; kb < 2; ++kb) {
      const v8h qj = *(const v8h*)(Qh + jA * 64 + kb * 32 + q * 8);
      v8h a;
#pragma unroll
      for (int i = 0; i < 8; ++i)
        a[i] = (f16)fmaxf(QiA[kb * 8 + i] - (float)qj[i], 0.f);
      uA[kb] = a;
    }
    // delta = relu(hp @ Wp2 + bp2)  (C layout) ; stash + LDS transpose
    float deltaC[16];
#pragma unroll
    for (int nb = 0; nb < 4; ++nb) {
      v4f c = {0.f, 0.f, 0.f, 0.f};
      c = __builtin_amdgcn_mfma_f32_16x16x32_f16(uA[0], fWp2[nb][0], c, 0, 0, 0);
      c = __builtin_amdgcn_mfma_f32_16x16x32_f16(uA[1], fWp2[nb][1], c, 0, 0, 0);
#pragma unroll
      for (int r = 0; r < 4; ++r) {
        const float d = fmaxf(c[r] + bp2C[nb], 0.f);
        deltaC[nb * 4 + r] = d;
        lds[w][0][(q * 4 + r) * 72 + p + 16 * nb] = (f16)d;
      }
    }
    // u = a_dst_i - a_src_j + delta  in A layout
#pragma unroll
    for (int kb = 0; kb < 2; ++kb) {
      const v8h dj = *(const v8h*)&lds[w][0][p * 72 + kb * 32 + q * 8];
      const v8h aj = *(const v8h*)(asrch + jA * 64 + kb * 32 + q * 8);
      v8h a;
#pragma unroll
      for (int i = 0; i < 8; ++i)
        a[i] = (f16)((adcA[kb * 8 + i] - (float)aj[i]) + (float)dj[i]);
      uA[kb] = a;
    }
    // ha = relu(u @ Wa1 + ba1) -> LDS transpose -> A layout
#pragma unroll
    for (int nb = 0; nb < 4; ++nb) {
      v4f c = {0.f, 0.f, 0.f, 0.f};
      c = __builtin_amdgcn_mfma_f32_16x16x32_f16(uA[0], fWa1[nb][0], c, 0, 0, 0);
      c = __builtin_amdgcn_mfma_f32_16x16x32_f16(uA[1], fWa1[nb][1], c, 0, 0, 0);
#pragma unroll
      for (int r = 0; r < 4; ++r)
        lds[w][1][(q * 4 + r) * 72 + p + 16 * nb] = (f16)fmaxf(c[r] + ba1C[nb], 0.f);
    }
#pragma unroll
    for (int kb = 0; kb < 2; ++kb)
      uA[kb] = *(const v8h*)&lds[w][1][p * 72 + kb * 32 + q * 8];
    // alpha = relu(ha @ Wa2 + ba2)  (C layout) + masked online softmax
#pragma unroll
    for (int nb = 0; nb < 4; ++nb) {
      v4f c = {0.f, 0.f, 0.f, 0.f};
      c = __builtin_amdgcn_mfma_f32_16x16x32_f16(uA[0], fWa2[nb][0], c, 0, 0, 0);
      c = __builtin_amdgcn_mfma_f32_16x16x32_f16(uA[1], fWa2[nb][1], c, 0, 0, 0);
      float al[4];
#pragma unroll
      for (int r = 0; r < 4; ++r)
        al[r] = okC[r] ? fmaxf(c[r] + ba2C[nb], 0.f) : -3.0e38f;
      float mn = m_[nb];
#pragma unroll
      for (int r = 0; r < 4; ++r) mn = fmaxf(mn, al[r]);
      const float sc = __expf(m_[nb] - mn);
      float ss = s_[nb] * sc;
      float aa = ac_[nb] * sc;
#pragma unroll
      for (int r = 0; r < 4; ++r) {
        const float wv = __expf(al[r] - mn);  // 0 for masked edges
        const float vj = v[jC[r] * 64 + p + 16 * nb];
        ss += wv;
        aa = fmaf(wv, vj + deltaC[nb * 4 + r], aa);
      }
      m_[nb] = mn; s_[nb] = ss; ac_[nb] = aa;
    }
  }
  // merge per-quad partial softmax states (channels identical across quads)
#pragma unroll
  for (int st = 16; st <= 32; st <<= 1) {
#pragma unroll
    for (int nb = 0; nb < 4; ++nb) {
      const float mo = __shfl_xor(m_[nb], st, 64);
      const float so = __shfl_xor(s_[nb], st, 64);
      const float ao = __shfl_xor(ac_[nb], st, 64);
      const float mn = fmaxf(m_[nb], mo);
      const float c1 = __expf(m_[nb] - mn), c2 = __expf(mo - mn);
      s_[nb] = s_[nb] * c1 + so * c2;
      ac_[nb] = ac_[nb] * c1 + ao * c2;
      m_[nb] = mn;
    }
  }
  if (q == 0) {
#pragma unroll
    for (int nb = 0; nb < 4; ++nb)
      o_pt[n * 64 + p + 16 * nb] = ac_[nb] / (s_[nb] + 1e-16f);
  }
}

// ---------------- epilogue (MFMA): out = relu(o_pt @ W_out + b_out) + x ------------

__global__ __launch_bounds__(256, 2) void k_out(
    const float* __restrict__ o_pt, const float* __restrict__ W_out,
    const float* __restrict__ b_out, const float* __restrict__ x,
    float* __restrict__ out) {
  const int lane = threadIdx.x & 63, w = threadIdx.x >> 6;
  const int q = lane >> 4, p = lane & 15;
  const int base = (blockIdx.x * 4 + w) * 16;
  if (base >= NN) return;
  v8h oa[2];
#pragma unroll
  for (int kb = 0; kb < 2; ++kb) {
    const float4 f0 = *(const float4*)(o_pt + (base + p) * 64 + kb * 32 + q * 8);
    const float4 f1 = *(const float4*)(o_pt + (base + p) * 64 + kb * 32 + q * 8 + 4);
    v8h a;
    a[0] = (f16)f0.x; a[1] = (f16)f0.y; a[2] = (f16)f0.z; a[3] = (f16)f0.w;
    a[4] = (f16)f1.x; a[5] = (f16)f1.y; a[6] = (f16)f1.z; a[7] = (f16)f1.w;
    oa[kb] = a;
  }
#pragma unroll
  for (int nb = 0; nb < 4; ++nb) {
    v4f c = {0.f, 0.f, 0.f, 0.f};
    c = __builtin_amdgcn_mfma_f32_16x16x32_f16(oa[0], bfrag64(W_out, 0, nb, q, p), c, 0, 0, 0);
    c = __builtin_amdgcn_mfma_f32_16x16x32_f16(oa[1], bfrag64(W_out, 1, nb, q, p), c, 0, 0, 0);
    const float bo = b_out[p + 16 * nb];
#pragma unroll
    for (int r = 0; r < 4; ++r) {
      const int idx = (base + q * 4 + r) * 64 + p + 16 * nb;
      out[idx] = fmaxf(c[r] + bo, 0.f) + x[idx];
    }
  }
}

// ---------------- launch ----------------

extern "C" void kernel_launch(void* const* d_in, const int* in_sizes, int n_in,
                              void* d_out, int out_size, void* d_ws, size_t ws_size,
                              hipStream_t stream) {
  const float* x     = (const float*)d_in[0];
  const float* pos   = (const float*)d_in[1];
  const int*   ei    = (const int*)d_in[2];
  const float* W_in  = (const float*)d_in[3];
  const float* b_in  = (const float*)d_in[4];
  const float* W_out = (const float*)d_in[5];
  const float* b_out = (const float*)d_in[6];
  const float* W_lin = (const float*)d_in[7];
  const float* W_src = (const float*)d_in[8];
  const float* W_dst = (const float*)d_in[9];
  const float* Wp1   = (const float*)d_in[10];
  const float* bp1   = (const float*)d_in[11];
  const float* Wp2   = (const float*)d_in[12];
  const float* bp2   = (const float*)d_in[13];
  const float* Wa1   = (const float*)d_in[14];
  const float* ba1   = (const float*)d_in[15];
  const float* Wa2   = (const float*)d_in[16];
  const float* ba2   = (const float*)d_in[17];

  float* a_dst = (float*)d_ws;                 // NN*64 f32
  float* vv    = a_dst + NN * 64;              // NN*64 f32
  float* o_pt  = vv + NN * 64;                 // NN*64 f32
  f16*  Qh     = (f16*)(o_pt + NN * 64);       // NN*64 f16
  f16*  asrch  = Qh + NN * 64;                 // NN*64 f16
  int*  deg    = (int*)(asrch + NN * 64);      // NN
  int* offsets = deg + NN;                     // NN+1
  int* cursor  = offsets + NN + 1;             // NN
  int* ssrc    = cursor + NN;                  // ETOT

  const int* esrc = ei;
  const int* edst = ei + NE;

  k_deg_init<<<(NN + 255) / 256, 256, 0, stream>>>(deg);
  k_node<<<(NN / 16 + 3) / 4, 256, 0, stream>>>(x, pos, W_in, b_in, W_lin, W_src,
                                                W_dst, Wp1, a_dst, vv, asrch, Qh);
  k_deg<<<(NE + 255) / 256, 256, 0, stream>>>(edst, deg);
  k_scan<<<1, 1024, 0, stream>>>(deg, offsets);
  k_self<<<(NN + 255) / 256, 256, 0, stream>>>(offsets, ssrc, cursor);
  k_scatter<<<(NE + 255) / 256, 256, 0, stream>>>(esrc, edst, cursor, ssrc);
  k_conv<<<NN / 4, 256, 0, stream>>>(Qh, bp1, Wp2, bp2, Wa1, ba1, Wa2, ba2,
                                     asrch, a_dst, vv, offsets, ssrc, o_pt);
  k_out<<<(NN / 16 + 3) / 4, 256, 0, stream>>>(o_pt, W_out, b_out, x, (float*)d_out);
}